// Round 1
// 135.226 us; speedup vs baseline: 1.1035x; 1.1035x over previous
//
#include <hip/hip_runtime.h>

// SpiralConv conv block: per-channel complex first-order recurrence
//   h[n] = c*h[n-1] + x[n],  h[-1] = last_conv_init[d],  out = Re(h)*x
// with c_d = exp(-exp(lmlg_d)) * e^{i*theta_d}.
//
// R5: occupancy fix. R4 ran 512 blocks (25% max occupancy, 13% measured;
// VALUBusy 11%, HBM 23% -> latency-bound). Now 1 channel/thread,
// grid = nc*B*(D/256) = 2048 blocks = 8192 waves = 100% of wave slots.
// Same math, same two-dispatch chunked-scan structure as R4.

#define L_  4096
#define B_  4
#define D_  1024
#define BD_ (B_ * D_)      // 4096 floats per time step

// ---------------------------------------------------------------- K1 -------
// One block per (chunk k, batch b, 256-channel slice db); 1 channel/thread.
// Chunk summary s = sum_j c^{ch-1-j} x[j]  (recurrence from 0 state).
__global__ __launch_bounds__(256) void sc_sum(
    const float* __restrict__ x,
    const float* __restrict__ lmlg,
    const float* __restrict__ theta,
    float2* __restrict__ ws, int ch) {
  const int t   = threadIdx.x;
  const int bid = blockIdx.x;
  const int db  = bid & 3;               // D/256 = 4 slices
  const int b   = (bid >> 2) & (B_ - 1);
  const int k   = bid >> 4;              // 16 blocks per chunk
  const int d   = (db << 8) + t;

  const float lg = lmlg[d], th = theta[d];
  const float g  = expf(-expf(lg));
  const float cr = g * cosf(th), ci = g * sinf(th);

  float sr = 0.f, si = 0.f;
  const float* xp = x + (size_t)k * ch * BD_ + (size_t)b * D_ + d;
#pragma unroll 8
  for (int j = 0; j < ch; ++j) {
    float xv = xp[(size_t)j * BD_];
    float nr = fmaf(cr, sr, fmaf(-ci, si, xv));
    float ni = fmaf(cr, si, ci * sr);
    sr = nr; si = ni;
  }
  ws[(size_t)(k * B_ + b) * D_ + d] = make_float2(sr, si);
}

// ---------------------------------------------------------------- K2 -------
// Same decomposition. Prefix-scan summaries 0..k-1 (L2-hot, 4 MiB buffer)
// to get the carry into chunk k, then replay the per-step recurrence over
// x and write out = Re(h)*x.
__global__ __launch_bounds__(256) void sc_out(
    const float* __restrict__ x,
    const float* __restrict__ lmlg,
    const float* __restrict__ theta,
    const float* __restrict__ init,
    const float2* __restrict__ ws,
    float* __restrict__ out, int ch) {
  const int t   = threadIdx.x;
  const int bid = blockIdx.x;
  const int db  = bid & 3;
  const int b   = (bid >> 2) & (B_ - 1);
  const int k   = bid >> 4;
  const int d   = (db << 8) + t;

  const float lg = lmlg[d], th = theta[d];
  const float e  = expf(lg);
  const float g  = expf(-e);
  const float cr = g * cosf(th), ci = g * sinf(th);

  // jump factor C = c^ch (computed from params, matches R4 numerics)
  const float chf = (float)ch;
  const float G   = expf(-e * chf);
  const float Cr  = G * cosf(th * chf), Ci = G * sinf(th * chf);

  // carry into chunk k: h = init; for kk<k: h = C*h + s[kk]
  float hr = init[d], hi = 0.f;
  const float2* sp = ws + (size_t)b * D_ + d;
#pragma unroll 4
  for (int kk = 0; kk < k; ++kk) {
    float2 s = sp[(size_t)kk * BD_];
    float nr = fmaf(Cr, hr, fmaf(-Ci, hi, s.x));
    float ni = fmaf(Cr, hi, fmaf(Ci, hr, s.y));
    hr = nr; hi = ni;
  }

  // replay recurrence over this chunk, emit out = Re(h)*x
  const size_t off = (size_t)k * ch * BD_ + (size_t)b * D_ + d;
  const float* xp = x + off;
  float*       op = out + off;
#pragma unroll 8
  for (int j = 0; j < ch; ++j) {
    float xv = xp[(size_t)j * BD_];
    float nr = fmaf(cr, hr, fmaf(-ci, hi, xv));
    float ni = fmaf(cr, hi, ci * hr);
    hr = nr; hi = ni;
    op[(size_t)j * BD_] = nr * xv;
  }
}

// ------------------------------------------------------------- fallback ----
// ws-free fully sequential per-column scan (used only if ws_size is tiny).
__global__ __launch_bounds__(256) void sc_full(
    const float* __restrict__ x, const float* __restrict__ lmlg,
    const float* __restrict__ theta, const float* __restrict__ init,
    float* __restrict__ out) {
  const int idx = blockIdx.x * 256 + threadIdx.x;   // column b*D+d
  const int d   = idx & (D_ - 1);
  float g = expf(-expf(lmlg[d]));
  float cr = g * cosf(theta[d]), ci = g * sinf(theta[d]);
  float hr = init[d], hi = 0.f;
  const float* xp = x + idx;
  float*       op = out + idx;
  for (int n = 0; n < L_; ++n) {
    float xv = xp[(size_t)n * BD_];
    float nr = fmaf(cr, hr, fmaf(-ci, hi, xv));
    float ni = fmaf(cr, hi, ci * hr);
    hr = nr; hi = ni;
    op[(size_t)n * BD_] = nr * xv;
  }
}

// ---------------------------------------------------------------------------
extern "C" void kernel_launch(void* const* d_in, const int* in_sizes, int n_in,
                              void* d_out, int out_size, void* d_ws, size_t ws_size,
                              hipStream_t stream) {
  const float* x     = (const float*)d_in[0];
  const float* lmlg  = (const float*)d_in[1];
  const float* theta = (const float*)d_in[2];
  const float* init  = (const float*)d_in[3];
  float*  out = (float*)d_out;
  float2* ws  = (float2*)d_ws;

  // largest pow2 chunk count whose summary rows fit in ws (row = 32 KiB)
  const size_t row_bytes = (size_t)BD_ * sizeof(float2);
  int nc = 128;
  while (nc > 1 && (size_t)nc * row_bytes > ws_size) nc >>= 1;

  if (nc >= 2 && (size_t)nc * row_bytes <= ws_size) {
    const int ch = L_ / nc;
    const int grid = nc * B_ * (D_ / 256);   // 2048 blocks @ nc=128
    sc_sum<<<grid, 256, 0, stream>>>(x, lmlg, theta, ws, ch);
    sc_out<<<grid, 256, 0, stream>>>(x, lmlg, theta, init, ws, out, ch);
  } else {
    sc_full<<<BD_ / 256, 256, 0, stream>>>(x, lmlg, theta, init, out);
  }
}